// Round 2
// baseline (970.175 us; speedup 1.0000x reference)
//
#include <hip/hip_runtime.h>
#include <hip/hip_bf16.h>

// GAT layer: N=50000, E=800000, IN=128, OUT=256, HEADS=8, C=32
// ws layout (floats):
//   h        : N*256
//   out_agg  : N*256
//   denom    : N*8      (contiguous with out_agg for a single memset)
//   a_src    : N*8
//   a_dst    : N*8
//   Bc       : 128*512  (packed [W | res_W^T])

__global__ __launch_bounds__(256) void pack_B_kernel(const float* __restrict__ W,
                                                     const float* __restrict__ resW,
                                                     float* __restrict__ Bc) {
    int id = blockIdx.x * 256 + threadIdx.x;   // 0..65535
    int k = id >> 9;          // 0..127
    int j = id & 511;         // 0..511
    float v;
    if (j < 256) v = W[k * 256 + j];
    else         v = resW[(j - 256) * 128 + k];
    Bc[id] = v;
}

// C = x[ N x 128 ] * Bc[ 128 x 512 ]; cols 0..255 -> h, cols 256..511 -> identity(+res_b)
__global__ __launch_bounds__(256) void gemm_kernel(const float* __restrict__ x,
                                                   const float* __restrict__ Bc,
                                                   const float* __restrict__ res_b,
                                                   float* __restrict__ h,
                                                   float* __restrict__ iden,
                                                   int N_) {
    __shared__ float As[64][68];
    __shared__ float Bs[64][68];
    const int tx = threadIdx.x & 15;
    const int ty = threadIdx.x >> 4;
    const int brow = blockIdx.x * 64;
    const int bcol = blockIdx.y * 64;
    float acc[4][4] = {};
    for (int k0 = 0; k0 < 128; k0 += 64) {
        #pragma unroll
        for (int p = 0; p < 4; ++p) {
            int r = ty + p * 16;
            int row = brow + r;
            float4 av = make_float4(0.f, 0.f, 0.f, 0.f);
            if (row < N_) av = *(const float4*)(x + (size_t)row * 128 + k0 + tx * 4);
            *(float4*)&As[r][tx * 4] = av;
            float4 bv = *(const float4*)(Bc + (size_t)(k0 + r) * 512 + bcol + tx * 4);
            *(float4*)&Bs[r][tx * 4] = bv;
        }
        __syncthreads();
        #pragma unroll 16
        for (int k = 0; k < 64; ++k) {
            float a[4], b[4];
            #pragma unroll
            for (int m = 0; m < 4; ++m) a[m] = As[ty + 16 * m][k];
            #pragma unroll
            for (int n = 0; n < 4; ++n) b[n] = Bs[k][tx + 16 * n];
            #pragma unroll
            for (int m = 0; m < 4; ++m)
                #pragma unroll
                for (int n = 0; n < 4; ++n)
                    acc[m][n] += a[m] * b[n];
        }
        __syncthreads();
    }
    #pragma unroll
    for (int m = 0; m < 4; ++m) {
        int row = brow + ty + 16 * m;
        if (row >= N_) continue;
        #pragma unroll
        for (int n = 0; n < 4; ++n) {
            int j = bcol + tx + 16 * n;
            if (j < 256) h[(size_t)row * 256 + j] = acc[m][n];
            else         iden[(size_t)row * 256 + (j - 256)] = acc[m][n] + res_b[j - 256];
        }
    }
}

// a_src[n,h] = sum_c h[n,h,c]*att_src[h,c]; same for dst. One thread per (n,head).
__global__ __launch_bounds__(256) void att_kernel(const float* __restrict__ h,
                                                  const float* __restrict__ att_src,
                                                  const float* __restrict__ att_dst,
                                                  float* __restrict__ a_src,
                                                  float* __restrict__ a_dst,
                                                  int N_) {
    int t = blockIdx.x * 256 + threadIdx.x;    // n*8 + head
    if (t >= N_ * 8) return;
    int hd = t & 7;
    int n  = t >> 3;
    const float4* hp = (const float4*)(h + (size_t)n * 256 + hd * 32);
    const float4* as = (const float4*)(att_src + hd * 32);
    const float4* ad = (const float4*)(att_dst + hd * 32);
    float ssum = 0.f, dsum = 0.f;
    #pragma unroll
    for (int i = 0; i < 8; ++i) {
        float4 hv = hp[i]; float4 a1 = as[i]; float4 a2 = ad[i];
        ssum += hv.x * a1.x + hv.y * a1.y + hv.z * a1.z + hv.w * a1.w;
        dsum += hv.x * a2.x + hv.y * a2.y + hv.z * a2.z + hv.w * a2.w;
    }
    a_src[t] = ssum;
    a_dst[t] = dsum;
}

// One wave per edge (incl. self-loops). Unnormalized exp weights; atomics into
// out_agg[dst,256] and denom[dst,8]. Max-subtraction skipped (cancels exactly).
// Edge indices are int32 (harness stages integer inputs as int32).
__global__ __launch_bounds__(256) void edge_kernel(const int* __restrict__ ei,
                                                   const float* __restrict__ a_src,
                                                   const float* __restrict__ a_dst,
                                                   const float* __restrict__ h,
                                                   float* __restrict__ out_agg,
                                                   float* __restrict__ denom,
                                                   int E_, int N_) {
    int wid  = (blockIdx.x * 256 + threadIdx.x) >> 6;
    int lane = threadIdx.x & 63;
    int total = E_ + N_;
    if (wid >= total) return;
    int s, d;
    if (wid < E_) {
        s = ei[wid];
        d = ei[E_ + wid];
    } else {
        s = d = wid - E_;
    }
    if ((unsigned)s >= (unsigned)N_ || (unsigned)d >= (unsigned)N_) return;  // safety
    float w8 = 0.f;
    if (lane < 8) {
        float e = a_src[s * 8 + lane] + a_dst[d * 8 + lane];
        e = e > 0.f ? e : 0.2f * e;
        w8 = __expf(e);
        atomicAdd(&denom[d * 8 + lane], w8);
    }
    size_t sbase = (size_t)s * 256, dbase = (size_t)d * 256;
    #pragma unroll
    for (int j = 0; j < 4; ++j) {
        int f = lane + 64 * j;
        float w = __shfl(w8, f >> 5);
        atomicAdd(&out_agg[dbase + f], w * h[sbase + f]);
    }
}

// One wave per node: divide by denom, +bias, LayerNorm, +identity (in d_out), ELU.
__global__ __launch_bounds__(256) void finalize_kernel(const float* __restrict__ out_agg,
                                                       const float* __restrict__ denom,
                                                       const float* __restrict__ bias,
                                                       const float* __restrict__ gamma,
                                                       const float* __restrict__ beta,
                                                       float* __restrict__ out,
                                                       int N_) {
    int lane = threadIdx.x & 63;
    int n = blockIdx.x * 4 + (threadIdx.x >> 6);
    if (n >= N_) return;
    float v[4];
    float sum = 0.f, sumsq = 0.f;
    #pragma unroll
    for (int j = 0; j < 4; ++j) {
        int f = lane + 64 * j;
        float den = denom[n * 8 + (f >> 5)];
        float val = out_agg[(size_t)n * 256 + f] / (den + 1e-16f) + bias[f];
        v[j] = val;
        sum += val;
        sumsq += val * val;
    }
    #pragma unroll
    for (int o = 32; o >= 1; o >>= 1) {
        sum   += __shfl_xor(sum, o);
        sumsq += __shfl_xor(sumsq, o);
    }
    float mean = sum * (1.f / 256.f);
    float var  = sumsq * (1.f / 256.f) - mean * mean;
    float inv  = rsqrtf(var + 1e-5f);
    #pragma unroll
    for (int j = 0; j < 4; ++j) {
        int f = lane + 64 * j;
        float y = gamma[f] * (v[j] - mean) * inv + beta[f];
        float z = y + out[(size_t)n * 256 + f];
        out[(size_t)n * 256 + f] = z > 0.f ? z : (__expf(z) - 1.f);
    }
}

extern "C" void kernel_launch(void* const* d_in, const int* in_sizes, int n_in,
                              void* d_out, int out_size, void* d_ws, size_t ws_size,
                              hipStream_t stream) {
    const float* x       = (const float*)d_in[0];
    const int*   ei      = (const int*)d_in[1];     // int32 per harness contract
    const float* W       = (const float*)d_in[2];
    const float* att_src = (const float*)d_in[3];
    const float* att_dst = (const float*)d_in[4];
    const float* bias    = (const float*)d_in[5];
    const float* gamma   = (const float*)d_in[6];
    const float* beta    = (const float*)d_in[7];
    const float* res_W   = (const float*)d_in[8];
    const float* res_b   = (const float*)d_in[9];
    float* out = (float*)d_out;

    const int N_ = in_sizes[0] / 128;   // 50000
    const int E_ = in_sizes[1] / 2;     // 800000

    float* ws      = (float*)d_ws;
    float* h       = ws;
    float* out_agg = h + (size_t)N_ * 256;
    float* denom   = out_agg + (size_t)N_ * 256;
    float* a_src   = denom + (size_t)N_ * 8;
    float* a_dst   = a_src + (size_t)N_ * 8;
    float* Bc      = a_dst + (size_t)N_ * 8;

    // zero the atomic accumulators (out_agg + denom are contiguous)
    hipMemsetAsync(out_agg, 0, ((size_t)N_ * 256 + (size_t)N_ * 8) * sizeof(float), stream);

    // pack [W | res_W^T] -> Bc
    pack_B_kernel<<<256, 256, 0, stream>>>(W, res_W, Bc);

    // fused GEMM: h = x@W ; identity = x@res_W^T + res_b (into d_out)
    dim3 ggrid((N_ + 63) / 64, 8);
    gemm_kernel<<<ggrid, 256, 0, stream>>>(x, Bc, res_b, h, out, N_);

    // attention logits per (node, head)
    att_kernel<<<(N_ * 8 + 255) / 256, 256, 0, stream>>>(h, att_src, att_dst, a_src, a_dst, N_);

    // edge scatter (one wave per edge, incl. self loops)
    int total_edges = E_ + N_;
    edge_kernel<<<(total_edges * 64 + 255) / 256, 256, 0, stream>>>(
        ei, a_src, a_dst, h, out_agg, denom, E_, N_);

    // finalize: divide, +bias, LN, +identity, ELU
    finalize_kernel<<<(N_ + 3) / 4, 256, 0, stream>>>(out_agg, denom, bias, gamma, beta, out, N_);
}

// Round 4
// 449.586 us; speedup vs baseline: 2.1579x; 2.1579x over previous
//
#include <hip/hip_runtime.h>
#include <hip/hip_bf16.h>

// GAT layer: N=50000, E=800000, IN=128, OUT=256, HEADS=8, C=32
// Strategy: device-built CSR (sort edges by dst) -> register-accumulating
// gather with fused LN/residual/ELU epilogue. No float atomics anywhere.
//
// ws layout:
//   h        : N*256 f
//   a_src    : N*8 f
//   a_dst    : N*8 f
//   Bc       : 128*512 f
//   deg      : N int      (histogram; repurposed as scatter cursor)
//   rowptr   : (N+1) int
//   partials : 256 int
//   col      : E int

__global__ __launch_bounds__(256) void pack_B_kernel(const float* __restrict__ W,
                                                     const float* __restrict__ resW,
                                                     float* __restrict__ Bc) {
    int id = blockIdx.x * 256 + threadIdx.x;   // 0..65535
    int k = id >> 9;          // 0..127
    int j = id & 511;         // 0..511
    float v;
    if (j < 256) v = W[k * 256 + j];
    else         v = resW[(j - 256) * 128 + k];
    Bc[id] = v;
}

// C = x[N x 128] * Bc[128 x 512]; cols 0..255 -> h, cols 256..511 -> identity(+res_b) into d_out
__global__ __launch_bounds__(256) void gemm_kernel(const float* __restrict__ x,
                                                   const float* __restrict__ Bc,
                                                   const float* __restrict__ res_b,
                                                   float* __restrict__ h,
                                                   float* __restrict__ iden,
                                                   int N_) {
    __shared__ float As[64][68];
    __shared__ float Bs[64][68];
    const int tx = threadIdx.x & 15;
    const int ty = threadIdx.x >> 4;
    const int brow = blockIdx.x * 64;
    const int bcol = blockIdx.y * 64;
    float acc[4][4] = {};
    for (int k0 = 0; k0 < 128; k0 += 64) {
        #pragma unroll
        for (int p = 0; p < 4; ++p) {
            int r = ty + p * 16;
            int row = brow + r;
            float4 av = make_float4(0.f, 0.f, 0.f, 0.f);
            if (row < N_) av = *(const float4*)(x + (size_t)row * 128 + k0 + tx * 4);
            *(float4*)&As[r][tx * 4] = av;
            float4 bv = *(const float4*)(Bc + (size_t)(k0 + r) * 512 + bcol + tx * 4);
            *(float4*)&Bs[r][tx * 4] = bv;
        }
        __syncthreads();
        #pragma unroll 16
        for (int k = 0; k < 64; ++k) {
            float a[4], b[4];
            #pragma unroll
            for (int m = 0; m < 4; ++m) a[m] = As[ty + 16 * m][k];
            #pragma unroll
            for (int n = 0; n < 4; ++n) b[n] = Bs[k][tx + 16 * n];
            #pragma unroll
            for (int m = 0; m < 4; ++m)
                #pragma unroll
                for (int n = 0; n < 4; ++n)
                    acc[m][n] += a[m] * b[n];
        }
        __syncthreads();
    }
    #pragma unroll
    for (int m = 0; m < 4; ++m) {
        int row = brow + ty + 16 * m;
        if (row >= N_) continue;
        #pragma unroll
        for (int n = 0; n < 4; ++n) {
            int j = bcol + tx + 16 * n;
            if (j < 256) h[(size_t)row * 256 + j] = acc[m][n];
            else         iden[(size_t)row * 256 + (j - 256)] = acc[m][n] + res_b[j - 256];
        }
    }
}

// a_src[n,h] / a_dst[n,h]: one thread per (n,head)
__global__ __launch_bounds__(256) void att_kernel(const float* __restrict__ h,
                                                  const float* __restrict__ att_src,
                                                  const float* __restrict__ att_dst,
                                                  float* __restrict__ a_src,
                                                  float* __restrict__ a_dst,
                                                  int N_) {
    int t = blockIdx.x * 256 + threadIdx.x;
    if (t >= N_ * 8) return;
    int hd = t & 7;
    int n  = t >> 3;
    const float4* hp = (const float4*)(h + (size_t)n * 256 + hd * 32);
    const float4* as = (const float4*)(att_src + hd * 32);
    const float4* ad = (const float4*)(att_dst + hd * 32);
    float ssum = 0.f, dsum = 0.f;
    #pragma unroll
    for (int i = 0; i < 8; ++i) {
        float4 hv = hp[i]; float4 a1 = as[i]; float4 a2 = ad[i];
        ssum += hv.x * a1.x + hv.y * a1.y + hv.z * a1.z + hv.w * a1.w;
        dsum += hv.x * a2.x + hv.y * a2.y + hv.z * a2.z + hv.w * a2.w;
    }
    a_src[t] = ssum;
    a_dst[t] = dsum;
}

// ---- CSR build ----
__global__ __launch_bounds__(256) void hist_kernel(const int* __restrict__ ei,
                                                   int* __restrict__ deg, int E_, int N_) {
    int i = blockIdx.x * 256 + threadIdx.x;
    if (i >= E_) return;
    int d = ei[E_ + i];
    if ((unsigned)d < (unsigned)N_) atomicAdd(&deg[d], 1);
}

// per-256-chunk sums
__global__ __launch_bounds__(256) void scan_part_kernel(const int* __restrict__ deg,
                                                        int* __restrict__ partials,
                                                        int N_) {
    __shared__ int tmp[256];
    int i = blockIdx.x * 256 + threadIdx.x;
    int v = (i < N_) ? deg[i] : 0;
    tmp[threadIdx.x] = v;
    __syncthreads();
    // tree reduce
    for (int off = 128; off >= 1; off >>= 1) {
        if (threadIdx.x < off) tmp[threadIdx.x] += tmp[threadIdx.x + off];
        __syncthreads();
    }
    if (threadIdx.x == 0) partials[blockIdx.x] = tmp[0];
}

// single-block exclusive scan of up to 256 partials (in place)
__global__ __launch_bounds__(256) void scan_top_kernel(int* __restrict__ partials, int nparts) {
    __shared__ int tmp[256];
    int t = threadIdx.x;
    int v = (t < nparts) ? partials[t] : 0;
    tmp[t] = v;
    __syncthreads();
    // Hillis-Steele inclusive
    for (int off = 1; off < 256; off <<= 1) {
        int x = (t >= off) ? tmp[t - off] : 0;
        __syncthreads();
        tmp[t] += x;
        __syncthreads();
    }
    if (t < nparts) partials[t] = tmp[t] - v;   // exclusive
}

// final: rowptr[i] = partials[b] + exclusive_scan_within_chunk; cursor := rowptr copy (reuse deg)
__global__ __launch_bounds__(256) void scan_final_kernel(int* __restrict__ deg,
                                                         const int* __restrict__ partials,
                                                         int* __restrict__ rowptr,
                                                         int N_) {
    __shared__ int tmp[256];
    int t = threadIdx.x;
    int i = blockIdx.x * 256 + t;
    int v = (i < N_) ? deg[i] : 0;
    tmp[t] = v;
    __syncthreads();
    for (int off = 1; off < 256; off <<= 1) {
        int x = (t >= off) ? tmp[t - off] : 0;
        __syncthreads();
        tmp[t] += x;
        __syncthreads();
    }
    int excl = tmp[t] - v + partials[blockIdx.x];
    if (i < N_) {
        rowptr[i] = excl;
        deg[i] = excl;                 // cursor
        if (i == N_ - 1) rowptr[N_] = excl + v;
    }
}

__global__ __launch_bounds__(256) void scatter_kernel(const int* __restrict__ ei,
                                                      int* __restrict__ cursor,
                                                      int* __restrict__ col,
                                                      int E_, int N_) {
    int i = blockIdx.x * 256 + threadIdx.x;
    if (i >= E_) return;
    int s = ei[i];
    int d = ei[E_ + i];
    if ((unsigned)s >= (unsigned)N_ || (unsigned)d >= (unsigned)N_) return;
    int pos = atomicAdd(&cursor[d], 1);
    col[pos] = s;
}

// ---- gather + finalize (fused): one wave per dst node ----
__global__ __launch_bounds__(256) void gather_finalize_kernel(
        const int* __restrict__ rowptr, const int* __restrict__ col,
        const float* __restrict__ h,
        const float* __restrict__ a_src, const float* __restrict__ a_dst,
        const float* __restrict__ bias, const float* __restrict__ gamma,
        const float* __restrict__ beta,
        float* __restrict__ out, int N_) {
    int n = blockIdx.x * 4 + (threadIdx.x >> 6);
    if (n >= N_) return;
    int lane = threadIdx.x & 63;
    int hd = lane >> 3;                 // head for this lane's float4 (f = lane*4)

    float adst = a_dst[n * 8 + hd];

    // self loop
    float es = a_src[n * 8 + hd] + adst;
    es = es > 0.f ? es : 0.2f * es;
    float w = __expf(es);
    float4 hv = *(const float4*)(h + (size_t)n * 256 + lane * 4);
    float accx = w * hv.x, accy = w * hv.y, accz = w * hv.z, accw = w * hv.w;
    float wsum = w;

    int beg = rowptr[n], end = rowptr[n + 1];
    for (int e0 = beg; e0 < end; e0 += 64) {
        int myc = (e0 + lane < end) ? col[e0 + lane] : 0;
        int cnt = min(64, end - e0);
        #pragma unroll 4
        for (int j = 0; j < cnt; ++j) {
            int s = __shfl(myc, j);
            float ea = a_src[s * 8 + hd] + adst;
            ea = ea > 0.f ? ea : 0.2f * ea;
            float we = __expf(ea);
            float4 hs = *(const float4*)(h + (size_t)s * 256 + lane * 4);
            accx += we * hs.x; accy += we * hs.y;
            accz += we * hs.z; accw += we * hs.w;
            wsum += we;
        }
    }

    float inv_w = 1.f / (wsum + 1e-16f);
    float4 b4 = *(const float4*)(bias + lane * 4);
    float v0 = accx * inv_w + b4.x;
    float v1 = accy * inv_w + b4.y;
    float v2 = accz * inv_w + b4.z;
    float v3 = accw * inv_w + b4.w;

    float sum = v0 + v1 + v2 + v3;
    float sumsq = v0 * v0 + v1 * v1 + v2 * v2 + v3 * v3;
    #pragma unroll
    for (int o = 32; o >= 1; o >>= 1) {
        sum   += __shfl_xor(sum, o);
        sumsq += __shfl_xor(sumsq, o);
    }
    float mean = sum * (1.f / 256.f);
    float var  = sumsq * (1.f / 256.f) - mean * mean;
    float inv  = rsqrtf(var + 1e-5f);

    float4 g4 = *(const float4*)(gamma + lane * 4);
    float4 be4 = *(const float4*)(beta + lane * 4);
    float4 id4 = *(const float4*)(out + (size_t)n * 256 + lane * 4);

    float y0 = g4.x * (v0 - mean) * inv + be4.x + id4.x;
    float y1 = g4.y * (v1 - mean) * inv + be4.y + id4.y;
    float y2 = g4.z * (v2 - mean) * inv + be4.z + id4.z;
    float y3 = g4.w * (v3 - mean) * inv + be4.w + id4.w;
    float4 r;
    r.x = y0 > 0.f ? y0 : (__expf(y0) - 1.f);
    r.y = y1 > 0.f ? y1 : (__expf(y1) - 1.f);
    r.z = y2 > 0.f ? y2 : (__expf(y2) - 1.f);
    r.w = y3 > 0.f ? y3 : (__expf(y3) - 1.f);
    *(float4*)(out + (size_t)n * 256 + lane * 4) = r;
}

extern "C" void kernel_launch(void* const* d_in, const int* in_sizes, int n_in,
                              void* d_out, int out_size, void* d_ws, size_t ws_size,
                              hipStream_t stream) {
    const float* x       = (const float*)d_in[0];
    const int*   ei      = (const int*)d_in[1];     // int32 per harness contract
    const float* W       = (const float*)d_in[2];
    const float* att_src = (const float*)d_in[3];
    const float* att_dst = (const float*)d_in[4];
    const float* bias    = (const float*)d_in[5];
    const float* gamma   = (const float*)d_in[6];
    const float* beta    = (const float*)d_in[7];
    const float* res_W   = (const float*)d_in[8];
    const float* res_b   = (const float*)d_in[9];
    float* out = (float*)d_out;

    const int N_ = in_sizes[0] / 128;   // 50000
    const int E_ = in_sizes[1] / 2;     // 800000

    float* ws     = (float*)d_ws;
    float* h      = ws;
    float* a_src  = h + (size_t)N_ * 256;
    float* a_dst  = a_src + (size_t)N_ * 8;
    float* Bc     = a_dst + (size_t)N_ * 8;
    int*   deg    = (int*)(Bc + 128 * 512);          // N ints (also cursor)
    int*   rowptr = deg + N_;                        // N+1 ints
    int*   parts  = rowptr + N_ + 1;                 // 256 ints
    int*   col    = parts + 256;                     // E ints

    const int nchunk = (N_ + 255) / 256;             // 196

    // --- CSR build ---
    hipMemsetAsync(deg, 0, (size_t)N_ * sizeof(int), stream);
    hist_kernel<<<(E_ + 255) / 256, 256, 0, stream>>>(ei, deg, E_, N_);
    scan_part_kernel<<<nchunk, 256, 0, stream>>>(deg, parts, N_);
    scan_top_kernel<<<1, 256, 0, stream>>>(parts, nchunk);
    scan_final_kernel<<<nchunk, 256, 0, stream>>>(deg, parts, rowptr, N_);
    scatter_kernel<<<(E_ + 255) / 256, 256, 0, stream>>>(ei, deg, col, E_, N_);

    // --- dense chain ---
    pack_B_kernel<<<256, 256, 0, stream>>>(W, res_W, Bc);
    dim3 ggrid((N_ + 63) / 64, 8);
    gemm_kernel<<<ggrid, 256, 0, stream>>>(x, Bc, res_b, h, out, N_);
    att_kernel<<<(N_ * 8 + 255) / 256, 256, 0, stream>>>(h, att_src, att_dst, a_src, a_dst, N_);

    // --- fused gather + LN + residual + ELU ---
    gather_finalize_kernel<<<(N_ + 3) / 4, 256, 0, stream>>>(
        rowptr, col, h, a_src, a_dst, bias, gamma, beta, out, N_);
}

// Round 5
// 329.886 us; speedup vs baseline: 2.9409x; 1.3629x over previous
//
#include <hip/hip_runtime.h>
#include <hip/hip_bf16.h>

// GAT layer: N=50000, E=800000, IN=128, OUT=256, HEADS=8, C=32
// R5: h stored bf16 (halves gather traffic); GEMM -> bf16 MFMA 16x16x32.
// CSR build (dst-sorted) -> register gather with fused LN/residual/ELU.
//
// ws layout (bytes, 16B-aligned regions):
//   xb   : N*128 u16   (bf16 x)
//   hb   : N*256 u16   (bf16 h)
//   Bt   : 512*128 u16 (bf16 [W | resW^T] transposed: Bt[j][k])
//   a_src: N*8 f32
//   a_dst: N*8 f32
//   deg  : N int (cursor)
//   rowptr:(N+1) int
//   parts: 256 int
//   col  : E int
// identity lives in d_out (f32), overwritten in place by gather_finalize.

typedef __attribute__((ext_vector_type(8))) __bf16 v8bf;
typedef __attribute__((ext_vector_type(4))) float  v4f;

__device__ __forceinline__ float bf2f(unsigned short u) {
    return __uint_as_float(((unsigned int)u) << 16);
}
__device__ __forceinline__ unsigned short f2bf(float f) {   // RNE
    unsigned int u = __float_as_uint(f);
    u = u + 0x7FFFu + ((u >> 16) & 1u);
    return (unsigned short)(u >> 16);
}

// ---- x -> bf16 ----
__global__ __launch_bounds__(256) void convert_x_kernel(const float* __restrict__ x,
                                                        unsigned short* __restrict__ xb,
                                                        int total4) {
    int t = blockIdx.x * 256 + threadIdx.x;
    if (t >= total4) return;
    float4 v = *(const float4*)(x + (size_t)t * 4);
    ushort4 o;
    o.x = f2bf(v.x); o.y = f2bf(v.y); o.z = f2bf(v.z); o.w = f2bf(v.w);
    *(ushort4*)(xb + (size_t)t * 4) = o;
}

// ---- pack Bt[j][k] = bf16( j<256 ? W[k][j] : resW[j-256][k] ) ----
__global__ __launch_bounds__(256) void pack_Bt_kernel(const float* __restrict__ W,
                                                      const float* __restrict__ resW,
                                                      unsigned short* __restrict__ Bt) {
    int id = blockIdx.x * 256 + threadIdx.x;   // 0..65535
    int j = id >> 7;          // 0..511
    int k = id & 127;
    float v = (j < 256) ? W[k * 256 + j] : resW[(size_t)(j - 256) * 128 + k];
    Bt[id] = f2bf(v);
}

// ---- bf16 MFMA GEMM: C[N x 512] = xb[N x 128] * Bt^T ----
// cols 0..255 -> hb (bf16); cols 256..511 -> iden(+res_b) f32 into d_out.
// Block: 256 thr = 4 waves (2x2), tile 64x64, full K=128 staged in LDS.
__global__ __launch_bounds__(256) void mfma_gemm_kernel(const unsigned short* __restrict__ xb,
                                                        const unsigned short* __restrict__ Bt,
                                                        const float* __restrict__ res_b,
                                                        unsigned short* __restrict__ hb,
                                                        float* __restrict__ iden,
                                                        int N_) {
    __shared__ unsigned short As[64][136];   // stride 136 u16 = 272B (16B-aligned, conflict-light)
    __shared__ unsigned short Bs[64][136];
    const int tid = threadIdx.x;
    const int brow = blockIdx.x * 64;
    const int bcol = blockIdx.y * 64;

    #pragma unroll
    for (int it = 0; it < 4; ++it) {
        int cid = it * 256 + tid;          // 0..1023
        int row = cid >> 4;                // 0..63
        int c   = cid & 15;                // 16B chunk
        int grow = brow + row;
        int4 av = make_int4(0, 0, 0, 0);
        if (grow < N_) av = *(const int4*)(xb + (size_t)grow * 128 + c * 8);
        *(int4*)&As[row][c * 8] = av;
        *(int4*)&Bs[row][c * 8] = *(const int4*)(Bt + (size_t)(bcol + row) * 128 + c * 8);
    }
    __syncthreads();

    const int lane = tid & 63;
    const int wid  = tid >> 6;
    const int wm = wid & 1;        // wave row (0..1)
    const int wn = wid >> 1;       // wave col (0..1)
    const int lm = lane & 15;
    const int lk = lane >> 4;      // 0..3

    v4f acc[2][2] = {};
    #pragma unroll
    for (int ks = 0; ks < 4; ++ks) {
        int koff = ks * 32 + lk * 8;
        v8bf a0 = *(const v8bf*)&As[wm * 32 + lm][koff];
        v8bf a1 = *(const v8bf*)&As[wm * 32 + 16 + lm][koff];
        v8bf b0 = *(const v8bf*)&Bs[wn * 32 + lm][koff];
        v8bf b1 = *(const v8bf*)&Bs[wn * 32 + 16 + lm][koff];
        acc[0][0] = __builtin_amdgcn_mfma_f32_16x16x32_bf16(a0, b0, acc[0][0], 0, 0, 0);
        acc[0][1] = __builtin_amdgcn_mfma_f32_16x16x32_bf16(a0, b1, acc[0][1], 0, 0, 0);
        acc[1][0] = __builtin_amdgcn_mfma_f32_16x16x32_bf16(a1, b0, acc[1][0], 0, 0, 0);
        acc[1][1] = __builtin_amdgcn_mfma_f32_16x16x32_bf16(a1, b1, acc[1][1], 0, 0, 0);
    }

    // C/D layout (m89-verified): col = lane&15, row = (lane>>4)*4 + reg
    const bool is_h = (bcol < 256);
    #pragma unroll
    for (int i = 0; i < 2; ++i) {
        #pragma unroll
        for (int j = 0; j < 2; ++j) {
            int col = bcol + wn * 32 + j * 16 + lm;
            float rb = is_h ? 0.f : res_b[col - 256];
            #pragma unroll
            for (int r = 0; r < 4; ++r) {
                int row = brow + wm * 32 + i * 16 + lk * 4 + r;
                if (row >= N_) continue;
                float v = acc[i][j][r];
                if (is_h) hb[(size_t)row * 256 + col] = f2bf(v);
                else      iden[(size_t)row * 256 + (col - 256)] = v + rb;
            }
        }
    }
}

// ---- attention logits: one thread per (n,head), h in bf16 ----
__global__ __launch_bounds__(256) void att_kernel(const unsigned short* __restrict__ hb,
                                                  const float* __restrict__ att_src,
                                                  const float* __restrict__ att_dst,
                                                  float* __restrict__ a_src,
                                                  float* __restrict__ a_dst,
                                                  int N_) {
    int t = blockIdx.x * 256 + threadIdx.x;
    if (t >= N_ * 8) return;
    int hd = t & 7;
    int n  = t >> 3;
    const ushort4* hp = (const ushort4*)(hb + (size_t)n * 256 + hd * 32);
    const float4* as = (const float4*)(att_src + hd * 32);
    const float4* ad = (const float4*)(att_dst + hd * 32);
    float ssum = 0.f, dsum = 0.f;
    #pragma unroll
    for (int i = 0; i < 8; ++i) {
        ushort4 hv = hp[i];
        float h0 = bf2f(hv.x), h1 = bf2f(hv.y), h2 = bf2f(hv.z), h3 = bf2f(hv.w);
        float4 a1 = as[i]; float4 a2 = ad[i];
        ssum += h0 * a1.x + h1 * a1.y + h2 * a1.z + h3 * a1.w;
        dsum += h0 * a2.x + h1 * a2.y + h2 * a2.z + h3 * a2.w;
    }
    a_src[t] = ssum;
    a_dst[t] = dsum;
}

// ---- CSR build ----
__global__ __launch_bounds__(256) void hist_kernel(const int* __restrict__ ei,
                                                   int* __restrict__ deg, int E_, int N_) {
    int i = blockIdx.x * 256 + threadIdx.x;
    if (i >= E_) return;
    int d = ei[E_ + i];
    if ((unsigned)d < (unsigned)N_) atomicAdd(&deg[d], 1);
}

__global__ __launch_bounds__(256) void scan_part_kernel(const int* __restrict__ deg,
                                                        int* __restrict__ partials,
                                                        int N_) {
    __shared__ int tmp[256];
    int i = blockIdx.x * 256 + threadIdx.x;
    int v = (i < N_) ? deg[i] : 0;
    tmp[threadIdx.x] = v;
    __syncthreads();
    for (int off = 128; off >= 1; off >>= 1) {
        if (threadIdx.x < off) tmp[threadIdx.x] += tmp[threadIdx.x + off];
        __syncthreads();
    }
    if (threadIdx.x == 0) partials[blockIdx.x] = tmp[0];
}

__global__ __launch_bounds__(256) void scan_top_kernel(int* __restrict__ partials, int nparts) {
    __shared__ int tmp[256];
    int t = threadIdx.x;
    int v = (t < nparts) ? partials[t] : 0;
    tmp[t] = v;
    __syncthreads();
    for (int off = 1; off < 256; off <<= 1) {
        int x = (t >= off) ? tmp[t - off] : 0;
        __syncthreads();
        tmp[t] += x;
        __syncthreads();
    }
    if (t < nparts) partials[t] = tmp[t] - v;   // exclusive
}

__global__ __launch_bounds__(256) void scan_final_kernel(int* __restrict__ deg,
                                                         const int* __restrict__ partials,
                                                         int* __restrict__ rowptr,
                                                         int N_) {
    __shared__ int tmp[256];
    int t = threadIdx.x;
    int i = blockIdx.x * 256 + t;
    int v = (i < N_) ? deg[i] : 0;
    tmp[t] = v;
    __syncthreads();
    for (int off = 1; off < 256; off <<= 1) {
        int x = (t >= off) ? tmp[t - off] : 0;
        __syncthreads();
        tmp[t] += x;
        __syncthreads();
    }
    int excl = tmp[t] - v + partials[blockIdx.x];
    if (i < N_) {
        rowptr[i] = excl;
        deg[i] = excl;                 // cursor
        if (i == N_ - 1) rowptr[N_] = excl + v;
    }
}

__global__ __launch_bounds__(256) void scatter_kernel(const int* __restrict__ ei,
                                                      int* __restrict__ cursor,
                                                      int* __restrict__ col,
                                                      int E_, int N_) {
    int i = blockIdx.x * 256 + threadIdx.x;
    if (i >= E_) return;
    int s = ei[i];
    int d = ei[E_ + i];
    if ((unsigned)s >= (unsigned)N_ || (unsigned)d >= (unsigned)N_) return;
    int pos = atomicAdd(&cursor[d], 1);
    col[pos] = s;
}

// ---- gather + finalize (fused): one wave per dst node, h in bf16 ----
__global__ __launch_bounds__(256) void gather_finalize_kernel(
        const int* __restrict__ rowptr, const int* __restrict__ col,
        const unsigned short* __restrict__ hb,
        const float* __restrict__ a_src, const float* __restrict__ a_dst,
        const float* __restrict__ bias, const float* __restrict__ gamma,
        const float* __restrict__ beta,
        float* __restrict__ out, int N_) {
    int n = blockIdx.x * 4 + (threadIdx.x >> 6);
    if (n >= N_) return;
    int lane = threadIdx.x & 63;
    int hd = lane >> 3;                 // head for this lane's 4 channels (f = lane*4)

    float adst = a_dst[n * 8 + hd];

    // self loop
    float es = a_src[n * 8 + hd] + adst;
    es = es > 0.f ? es : 0.2f * es;
    float w = __expf(es);
    ushort4 hv = *(const ushort4*)(hb + (size_t)n * 256 + lane * 4);
    float accx = w * bf2f(hv.x), accy = w * bf2f(hv.y);
    float accz = w * bf2f(hv.z), accw = w * bf2f(hv.w);
    float wsum = w;

    int beg = rowptr[n], end = rowptr[n + 1];
    for (int e0 = beg; e0 < end; e0 += 64) {
        int myc = (e0 + lane < end) ? col[e0 + lane] : 0;
        int cnt = min(64, end - e0);
        #pragma unroll 4
        for (int j = 0; j < cnt; ++j) {
            int s = __shfl(myc, j);
            float ea = a_src[s * 8 + hd] + adst;
            ea = ea > 0.f ? ea : 0.2f * ea;
            float we = __expf(ea);
            ushort4 hs = *(const ushort4*)(hb + (size_t)s * 256 + lane * 4);
            accx += we * bf2f(hs.x); accy += we * bf2f(hs.y);
            accz += we * bf2f(hs.z); accw += we * bf2f(hs.w);
            wsum += we;
        }
    }

    float inv_w = 1.f / (wsum + 1e-16f);
    float4 b4 = *(const float4*)(bias + lane * 4);
    float v0 = accx * inv_w + b4.x;
    float v1 = accy * inv_w + b4.y;
    float v2 = accz * inv_w + b4.z;
    float v3 = accw * inv_w + b4.w;

    float sum = v0 + v1 + v2 + v3;
    float sumsq = v0 * v0 + v1 * v1 + v2 * v2 + v3 * v3;
    #pragma unroll
    for (int o = 32; o >= 1; o >>= 1) {
        sum   += __shfl_xor(sum, o);
        sumsq += __shfl_xor(sumsq, o);
    }
    float mean = sum * (1.f / 256.f);
    float var  = sumsq * (1.f / 256.f) - mean * mean;
    float inv  = rsqrtf(var + 1e-5f);

    float4 g4  = *(const float4*)(gamma + lane * 4);
    float4 be4 = *(const float4*)(beta + lane * 4);
    float4 id4 = *(const float4*)(out + (size_t)n * 256 + lane * 4);

    float y0 = g4.x * (v0 - mean) * inv + be4.x + id4.x;
    float y1 = g4.y * (v1 - mean) * inv + be4.y + id4.y;
    float y2 = g4.z * (v2 - mean) * inv + be4.z + id4.z;
    float y3 = g4.w * (v3 - mean) * inv + be4.w + id4.w;
    float4 r;
    r.x = y0 > 0.f ? y0 : (__expf(y0) - 1.f);
    r.y = y1 > 0.f ? y1 : (__expf(y1) - 1.f);
    r.z = y2 > 0.f ? y2 : (__expf(y2) - 1.f);
    r.w = y3 > 0.f ? y3 : (__expf(y3) - 1.f);
    *(float4*)(out + (size_t)n * 256 + lane * 4) = r;
}

extern "C" void kernel_launch(void* const* d_in, const int* in_sizes, int n_in,
                              void* d_out, int out_size, void* d_ws, size_t ws_size,
                              hipStream_t stream) {
    const float* x       = (const float*)d_in[0];
    const int*   ei      = (const int*)d_in[1];     // int32 per harness contract
    const float* W       = (const float*)d_in[2];
    const float* att_src = (const float*)d_in[3];
    const float* att_dst = (const float*)d_in[4];
    const float* bias    = (const float*)d_in[5];
    const float* gamma   = (const float*)d_in[6];
    const float* beta    = (const float*)d_in[7];
    const float* res_W   = (const float*)d_in[8];
    const float* res_b   = (const float*)d_in[9];
    float* out = (float*)d_out;

    const int N_ = in_sizes[0] / 128;   // 50000
    const int E_ = in_sizes[1] / 2;     // 800000

    unsigned short* xb = (unsigned short*)d_ws;          // N*128 u16
    unsigned short* hb = xb + (size_t)N_ * 128;          // N*256 u16
    unsigned short* Bt = hb + (size_t)N_ * 256;          // 512*128 u16
    float* a_src  = (float*)(Bt + 512 * 128);            // N*8 f
    float* a_dst  = a_src + (size_t)N_ * 8;              // N*8 f
    int*   deg    = (int*)(a_dst + (size_t)N_ * 8);      // N int (cursor)
    int*   rowptr = deg + N_;                            // N+1 int
    int*   parts  = rowptr + N_ + 1;                     // 256 int
    int*   col    = parts + 256;                         // E int

    const int nchunk = (N_ + 255) / 256;                 // 196

    // --- CSR build ---
    hipMemsetAsync(deg, 0, (size_t)N_ * sizeof(int), stream);
    hist_kernel<<<(E_ + 255) / 256, 256, 0, stream>>>(ei, deg, E_, N_);
    scan_part_kernel<<<nchunk, 256, 0, stream>>>(deg, parts, N_);
    scan_top_kernel<<<1, 256, 0, stream>>>(parts, nchunk);
    scan_final_kernel<<<nchunk, 256, 0, stream>>>(deg, parts, rowptr, N_);
    scatter_kernel<<<(E_ + 255) / 256, 256, 0, stream>>>(ei, deg, col, E_, N_);

    // --- dense chain (bf16 MFMA) ---
    int total4 = N_ * 128 / 4;
    convert_x_kernel<<<(total4 + 255) / 256, 256, 0, stream>>>(x, xb, total4);
    pack_Bt_kernel<<<256, 256, 0, stream>>>(W, res_W, Bt);
    dim3 ggrid((N_ + 63) / 64, 8);
    mfma_gemm_kernel<<<ggrid, 256, 0, stream>>>(xb, Bt, res_b, hb, out, N_);
    att_kernel<<<(N_ * 8 + 255) / 256, 256, 0, stream>>>(hb, att_src, att_dst, a_src, a_dst, N_);

    // --- fused gather + LN + residual + ELU ---
    gather_finalize_kernel<<<(N_ + 3) / 4, 256, 0, stream>>>(
        rowptr, col, hb, a_src, a_dst, bias, gamma, beta, out, N_);
}

// Round 8
// 308.305 us; speedup vs baseline: 3.1468x; 1.0700x over previous
//
#include <hip/hip_runtime.h>
#include <hip/hip_bf16.h>

// GAT layer: N=50000, E=800000, IN=128, OUT=256, HEADS=8, C=32
// R6: single-pass MFMA GEMM (block = 64-row stripe, loops 8 col-tiles;
// x converted to bf16 during LDS staging; coalesced epilogue via LDS tile;
// a_src/a_dst fused into the GEMM epilogue). CSR gather unchanged.
//
// ws layout:
//   hb    : N*256 u16 (bf16 h)
//   Bt    : 512*128 u16 (bf16 [W | resW^T] transposed: Bt[j][k])
//   a_src : N*8 f32
//   a_dst : N*8 f32
//   deg   : N int (cursor)
//   rowptr: (N+1) int
//   parts : 256 int
//   col   : E int
// identity lives in d_out (f32), overwritten in place by gather_finalize.

typedef __attribute__((ext_vector_type(8))) __bf16 v8bf;
typedef __attribute__((ext_vector_type(4))) float  v4f;

__device__ __forceinline__ float bf2f(unsigned short u) {
    return __uint_as_float(((unsigned int)u) << 16);
}
__device__ __forceinline__ unsigned short f2bf(float f) {   // RNE
    unsigned int u = __float_as_uint(f);
    u = u + 0x7FFFu + ((u >> 16) & 1u);
    return (unsigned short)(u >> 16);
}

// ---- pack Bt[j][k] = bf16( j<256 ? W[k][j] : resW[j-256][k] ) ----
__global__ __launch_bounds__(256) void pack_Bt_kernel(const float* __restrict__ W,
                                                      const float* __restrict__ resW,
                                                      unsigned short* __restrict__ Bt) {
    int id = blockIdx.x * 256 + threadIdx.x;   // 0..65535
    int j = id >> 7;          // 0..511
    int k = id & 127;
    float v = (j < 256) ? W[k * 256 + j] : resW[(size_t)(j - 256) * 128 + k];
    Bt[id] = f2bf(v);
}

// ---- fused MFMA GEMM + att logits ----
// One block per 64-row stripe; loops over 8 col-tiles of 64.
// cols 0..255 -> hb (bf16) + a_src/a_dst partial dots; 256..511 -> iden(+res_b) f32.
__global__ __launch_bounds__(256) void mfma_gemm_kernel(const float* __restrict__ x,
                                                        const unsigned short* __restrict__ Bt,
                                                        const float* __restrict__ att_src,
                                                        const float* __restrict__ att_dst,
                                                        const float* __restrict__ res_b,
                                                        unsigned short* __restrict__ hb,
                                                        float* __restrict__ iden,
                                                        float* __restrict__ a_src,
                                                        float* __restrict__ a_dst,
                                                        int N_) {
    __shared__ unsigned short As[64][136];   // bf16 A stripe, staged once
    __shared__ unsigned short Bs[64][136];   // bf16 B col-tile, re-staged per iter
    __shared__ float Cs[64][68];             // f32 64x64 epilogue staging
    const int tid = threadIdx.x;
    const int brow = blockIdx.x * 64;

    // ---- stage A (convert f32 -> bf16 in flight) ----
    #pragma unroll
    for (int it = 0; it < 4; ++it) {
        int cid = it * 256 + tid;          // 0..1023 chunks of 8 bf16
        int row = cid >> 4;
        int c   = cid & 15;                // 8-elem chunk
        int grow = brow + row;
        unsigned int w[4];
        if (grow < N_) {
            const float4* xp = (const float4*)(x + (size_t)grow * 128 + c * 8);
            float4 v0 = xp[0], v1 = xp[1];
            w[0] = (unsigned)f2bf(v0.x) | ((unsigned)f2bf(v0.y) << 16);
            w[1] = (unsigned)f2bf(v0.z) | ((unsigned)f2bf(v0.w) << 16);
            w[2] = (unsigned)f2bf(v1.x) | ((unsigned)f2bf(v1.y) << 16);
            w[3] = (unsigned)f2bf(v1.z) | ((unsigned)f2bf(v1.w) << 16);
        } else {
            w[0] = w[1] = w[2] = w[3] = 0u;
        }
        *(int4*)&As[row][c * 8] = make_int4(w[0], w[1], w[2], w[3]);
    }

    const int lane = tid & 63;
    const int wid  = tid >> 6;
    const int wm = wid & 1;        // wave row (0..1)
    const int wn = wid >> 1;       // wave col (0..1)
    const int lm = lane & 15;
    const int lk = lane >> 4;      // 0..3

    const int tRow = tid >> 2;           // store-phase row 0..63
    const int tcc  = (tid & 3) * 16;     // store-phase col chunk

    v8bf afr[4][2];                      // A fragments, hoisted across col-tiles
    bool afr_loaded = false;

    #pragma unroll 1
    for (int bc = 0; bc < 8; ++bc) {
        // ---- stage B col-tile ----
        #pragma unroll
        for (int it = 0; it < 4; ++it) {
            int cid = it * 256 + tid;
            int row = cid >> 4;
            int c   = cid & 15;
            *(int4*)&Bs[row][c * 8] =
                *(const int4*)(Bt + (size_t)(bc * 64 + row) * 128 + c * 8);
        }
        __syncthreads();

        if (!afr_loaded) {
            afr_loaded = true;
            #pragma unroll
            for (int ks = 0; ks < 4; ++ks) {
                int koff = ks * 32 + lk * 8;
                afr[ks][0] = *(const v8bf*)&As[wm * 32 + lm][koff];
                afr[ks][1] = *(const v8bf*)&As[wm * 32 + 16 + lm][koff];
            }
        }

        v4f acc[2][2] = {};
        #pragma unroll
        for (int ks = 0; ks < 4; ++ks) {
            int koff = ks * 32 + lk * 8;
            v8bf b0 = *(const v8bf*)&Bs[wn * 32 + lm][koff];
            v8bf b1 = *(const v8bf*)&Bs[wn * 32 + 16 + lm][koff];
            acc[0][0] = __builtin_amdgcn_mfma_f32_16x16x32_bf16(afr[ks][0], b0, acc[0][0], 0, 0, 0);
            acc[0][1] = __builtin_amdgcn_mfma_f32_16x16x32_bf16(afr[ks][0], b1, acc[0][1], 0, 0, 0);
            acc[1][0] = __builtin_amdgcn_mfma_f32_16x16x32_bf16(afr[ks][1], b0, acc[1][0], 0, 0, 0);
            acc[1][1] = __builtin_amdgcn_mfma_f32_16x16x32_bf16(afr[ks][1], b1, acc[1][1], 0, 0, 0);
        }

        // C/D layout (m89-verified): col = lane&15, row = (lane>>4)*4 + reg
        #pragma unroll
        for (int i = 0; i < 2; ++i)
            #pragma unroll
            for (int j = 0; j < 2; ++j)
                #pragma unroll
                for (int r = 0; r < 4; ++r)
                    Cs[wm * 32 + i * 16 + lk * 4 + r][wn * 32 + j * 16 + lm] = acc[i][j][r];
        __syncthreads();

        // ---- coalesced store phase ----
        int grow = brow + tRow;
        if (grow < N_) {
            int gcol = bc * 64 + tcc;
            float vs[16];
            #pragma unroll
            for (int q = 0; q < 4; ++q) {
                float4 t4 = *(const float4*)&Cs[tRow][tcc + q * 4];
                vs[q * 4 + 0] = t4.x; vs[q * 4 + 1] = t4.y;
                vs[q * 4 + 2] = t4.z; vs[q * 4 + 3] = t4.w;
            }
            if (gcol < 256) {
                // att partial dots (head = gcol>>5; this thread covers 16 of its 32 ch)
                int head = gcol >> 5;
                int chb  = gcol & 31;     // 0 or 16
                float ps = 0.f, pd = 0.f;
                #pragma unroll
                for (int c = 0; c < 16; ++c) {
                    ps += vs[c] * att_src[head * 32 + chb + c];
                    pd += vs[c] * att_dst[head * 32 + chb + c];
                }
                ps += __shfl_xor(ps, 1);
                pd += __shfl_xor(pd, 1);
                if (!(tid & 1)) {
                    a_src[grow * 8 + head] = ps;
                    a_dst[grow * 8 + head] = pd;
                }
                unsigned int w[8];
                #pragma unroll
                for (int c = 0; c < 8; ++c)
                    w[c] = (unsigned)f2bf(vs[2 * c]) | ((unsigned)f2bf(vs[2 * c + 1]) << 16);
                unsigned short* hp = hb + (size_t)grow * 256 + gcol;
                *(int4*)hp       = make_int4(w[0], w[1], w[2], w[3]);
                *(int4*)(hp + 8) = make_int4(w[4], w[5], w[6], w[7]);
            } else {
                int oc = gcol - 256;
                float* ip = iden + (size_t)grow * 256 + oc;
                #pragma unroll
                for (int q = 0; q < 4; ++q) {
                    float4 v = make_float4(vs[q * 4 + 0], vs[q * 4 + 1],
                                           vs[q * 4 + 2], vs[q * 4 + 3]);
                    const float4 rb = *(const float4*)(res_b + oc + q * 4);
                    v.x += rb.x; v.y += rb.y; v.z += rb.z; v.w += rb.w;
                    *(float4*)(ip + q * 4) = v;
                }
            }
        }
        __syncthreads();
    }
}

// ---- CSR build ----
__global__ __launch_bounds__(256) void hist_kernel(const int* __restrict__ ei,
                                                   int* __restrict__ deg, int E_, int N_) {
    int i = blockIdx.x * 256 + threadIdx.x;
    if (i >= E_) return;
    int d = ei[E_ + i];
    if ((unsigned)d < (unsigned)N_) atomicAdd(&deg[d], 1);
}

__global__ __launch_bounds__(256) void scan_part_kernel(const int* __restrict__ deg,
                                                        int* __restrict__ partials,
                                                        int N_) {
    __shared__ int tmp[256];
    int i = blockIdx.x * 256 + threadIdx.x;
    int v = (i < N_) ? deg[i] : 0;
    tmp[threadIdx.x] = v;
    __syncthreads();
    for (int off = 128; off >= 1; off >>= 1) {
        if (threadIdx.x < off) tmp[threadIdx.x] += tmp[threadIdx.x + off];
        __syncthreads();
    }
    if (threadIdx.x == 0) partials[blockIdx.x] = tmp[0];
}

__global__ __launch_bounds__(256) void scan_top_kernel(int* __restrict__ partials, int nparts) {
    __shared__ int tmp[256];
    int t = threadIdx.x;
    int v = (t < nparts) ? partials[t] : 0;
    tmp[t] = v;
    __syncthreads();
    for (int off = 1; off < 256; off <<= 1) {
        int x = (t >= off) ? tmp[t - off] : 0;
        __syncthreads();
        tmp[t] += x;
        __syncthreads();
    }
    if (t < nparts) partials[t] = tmp[t] - v;   // exclusive
}

__global__ __launch_bounds__(256) void scan_final_kernel(int* __restrict__ deg,
                                                         const int* __restrict__ partials,
                                                         int* __restrict__ rowptr,
                                                         int N_) {
    __shared__ int tmp[256];
    int t = threadIdx.x;
    int i = blockIdx.x * 256 + t;
    int v = (i < N_) ? deg[i] : 0;
    tmp[t] = v;
    __syncthreads();
    for (int off = 1; off < 256; off <<= 1) {
        int x = (t >= off) ? tmp[t - off] : 0;
        __syncthreads();
        tmp[t] += x;
        __syncthreads();
    }
    int excl = tmp[t] - v + partials[blockIdx.x];
    if (i < N_) {
        rowptr[i] = excl;
        deg[i] = excl;                 // cursor
        if (i == N_ - 1) rowptr[N_] = excl + v;
    }
}

__global__ __launch_bounds__(256) void scatter_kernel(const int* __restrict__ ei,
                                                      int* __restrict__ cursor,
                                                      int* __restrict__ col,
                                                      int E_, int N_) {
    int i = blockIdx.x * 256 + threadIdx.x;
    if (i >= E_) return;
    int s = ei[i];
    int d = ei[E_ + i];
    if ((unsigned)s >= (unsigned)N_ || (unsigned)d >= (unsigned)N_) return;
    int pos = atomicAdd(&cursor[d], 1);
    col[pos] = s;
}

// ---- gather + finalize (fused): one wave per dst node, h in bf16 ----
__global__ __launch_bounds__(256) void gather_finalize_kernel(
        const int* __restrict__ rowptr, const int* __restrict__ col,
        const unsigned short* __restrict__ hb,
        const float* __restrict__ a_src, const float* __restrict__ a_dst,
        const float* __restrict__ bias, const float* __restrict__ gamma,
        const float* __restrict__ beta,
        float* __restrict__ out, int N_) {
    int n = blockIdx.x * 4 + (threadIdx.x >> 6);
    if (n >= N_) return;
    int lane = threadIdx.x & 63;
    int hd = lane >> 3;                 // head for this lane's 4 channels (f = lane*4)

    float adst = a_dst[n * 8 + hd];

    // self loop
    float es = a_src[n * 8 + hd] + adst;
    es = es > 0.f ? es : 0.2f * es;
    float w = __expf(es);
    ushort4 hv = *(const ushort4*)(hb + (size_t)n * 256 + lane * 4);
    float accx = w * bf2f(hv.x), accy = w * bf2f(hv.y);
    float accz = w * bf2f(hv.z), accw = w * bf2f(hv.w);
    float wsum = w;

    int beg = rowptr[n], end = rowptr[n + 1];
    for (int e0 = beg; e0 < end; e0 += 64) {
        int myc = (e0 + lane < end) ? col[e0 + lane] : 0;
        int cnt = min(64, end - e0);
        #pragma unroll 4
        for (int j = 0; j < cnt; ++j) {
            int s = __shfl(myc, j);
            float ea = a_src[s * 8 + hd] + adst;
            ea = ea > 0.f ? ea : 0.2f * ea;
            float we = __expf(ea);
            ushort4 hs = *(const ushort4*)(hb + (size_t)s * 256 + lane * 4);
            accx += we * bf2f(hs.x); accy += we * bf2f(hs.y);
            accz += we * bf2f(hs.z); accw += we * bf2f(hs.w);
            wsum += we;
        }
    }

    float inv_w = 1.f / (wsum + 1e-16f);
    float4 b4 = *(const float4*)(bias + lane * 4);
    float v0 = accx * inv_w + b4.x;
    float v1 = accy * inv_w + b4.y;
    float v2 = accz * inv_w + b4.z;
    float v3 = accw * inv_w + b4.w;

    float sum = v0 + v1 + v2 + v3;
    float sumsq = v0 * v0 + v1 * v1 + v2 * v2 + v3 * v3;
    #pragma unroll
    for (int o = 32; o >= 1; o >>= 1) {
        sum   += __shfl_xor(sum, o);
        sumsq += __shfl_xor(sumsq, o);
    }
    float mean = sum * (1.f / 256.f);
    float var  = sumsq * (1.f / 256.f) - mean * mean;
    float inv  = rsqrtf(var + 1e-5f);

    float4 g4  = *(const float4*)(gamma + lane * 4);
    float4 be4 = *(const float4*)(beta + lane * 4);
    float4 id4 = *(const float4*)(out + (size_t)n * 256 + lane * 4);

    float y0 = g4.x * (v0 - mean) * inv + be4.x + id4.x;
    float y1 = g4.y * (v1 - mean) * inv + be4.y + id4.y;
    float y2 = g4.z * (v2 - mean) * inv + be4.z + id4.z;
    float y3 = g4.w * (v3 - mean) * inv + be4.w + id4.w;
    float4 r;
    r.x = y0 > 0.f ? y0 : (__expf(y0) - 1.f);
    r.y = y1 > 0.f ? y1 : (__expf(y1) - 1.f);
    r.z = y2 > 0.f ? y2 : (__expf(y2) - 1.f);
    r.w = y3 > 0.f ? y3 : (__expf(y3) - 1.f);
    *(float4*)(out + (size_t)n * 256 + lane * 4) = r;
}

extern "C" void kernel_launch(void* const* d_in, const int* in_sizes, int n_in,
                              void* d_out, int out_size, void* d_ws, size_t ws_size,
                              hipStream_t stream) {
    const float* x       = (const float*)d_in[0];
    const int*   ei      = (const int*)d_in[1];     // int32 per harness contract
    const float* W       = (const float*)d_in[2];
    const float* att_src = (const float*)d_in[3];
    const float* att_dst = (const float*)d_in[4];
    const float* bias    = (const float*)d_in[5];
    const float* gamma   = (const float*)d_in[6];
    const float* beta    = (const float*)d_in[7];
    const float* res_W   = (const float*)d_in[8];
    const float* res_b   = (const float*)d_in[9];
    float* out = (float*)d_out;

    const int N_ = in_sizes[0] / 128;   // 50000
    const int E_ = in_sizes[1] / 2;     // 800000

    unsigned short* hb = (unsigned short*)d_ws;          // N*256 u16
    unsigned short* Bt = hb + (size_t)N_ * 256;          // 512*128 u16
    float* a_src  = (float*)(Bt + 512 * 128);            // N*8 f
    float* a_dst  = a_src + (size_t)N_ * 8;              // N*8 f
    int*   deg    = (int*)(a_dst + (size_t)N_ * 8);      // N int (cursor)
    int*   rowptr = deg + N_;                            // N+1 int
    int*   parts  = rowptr + N_ + 1;                     // 256 int
    int*   col    = parts + 256;                         // E int

    const int nchunk = (N_ + 255) / 256;                 // 196

    // --- CSR build ---
    hipMemsetAsync(deg, 0, (size_t)N_ * sizeof(int), stream);
    hist_kernel<<<(E_ + 255) / 256, 256, 0, stream>>>(ei, deg, E_, N_);
    scan_part_kernel<<<nchunk, 256, 0, stream>>>(deg, parts, N_);
    scan_top_kernel<<<1, 256, 0, stream>>>(parts, nchunk);
    scan_final_kernel<<<nchunk, 256, 0, stream>>>(deg, parts, rowptr, N_);
    scatter_kernel<<<(E_ + 255) / 256, 256, 0, stream>>>(ei, deg, col, E_, N_);

    // --- dense chain: pack Bt, fused GEMM(+att logits) ---
    pack_Bt_kernel<<<256, 256, 0, stream>>>(W, res_W, Bt);
    mfma_gemm_kernel<<<(N_ + 63) / 64, 256, 0, stream>>>(
        x, Bt, att_src, att_dst, res_b, hb, out, a_src, a_dst, N_);

    // --- fused gather + LN + residual + ELU ---
    gather_finalize_kernel<<<(N_ + 3) / 4, 256, 0, stream>>>(
        rowptr, col, hb, a_src, a_dst, bias, gamma, beta, out, N_);
}